// Round 19
// baseline (316.073 us; speedup 1.0000x reference)
//
#include <hip/hip_runtime.h>
#include <stdint.h>

#define B_ 4
#define T_ 500
#define L_ 120000
#define NH_ 100
// RWR(16) level sizes (verified R9 — DO NOT TOUCH)
#define N1_ 7500
#define N2_ 469
#define N2P_ 7504
#define N3_ 30
#define N3P_ 480
#define N4_ 2
#define N4P_ 32

#define ACT_NONE 0
#define ACT_LRELU 1
#define ACT_SOFTPLUS 2
#define ACT_SIGMOID 3

#define CH 16             // cc chunk
#define ROWS 260          // x row stride (258 used: t0-1 .. t0+256)
#define XN 4352           // x region extent = 17*256 staging slots (rows use 4160)
#define WN 768            // weight floats per buffer (conv3 16cc*16o*3; dwpw uses 512)
#define BUFA (XN + WN)    // 5120 floats per buffer; 2 bufs = 40960 B

typedef const __attribute__((address_space(1))) void* gp1_t;
typedef __attribute__((address_space(3))) void* lp3_t;

// ---------------- Threefry2x32-20 (verified R9) ----------------
__host__ __device__ __forceinline__ uint32_t tf_rotl(uint32_t v, int d) {
  return (v << d) | (v >> (32 - d));
}
__host__ __device__ __forceinline__ void tf_block(uint32_t k0, uint32_t k1,
                                                  uint32_t& x0, uint32_t& x1) {
  uint32_t k2 = k0 ^ k1 ^ 0x1BD11BDAu;
  x0 += k0; x1 += k1;
#define TF_R(d) x0 += x1; x1 = tf_rotl(x1, (d)); x1 ^= x0;
  TF_R(13) TF_R(15) TF_R(26) TF_R(6)   x0 += k1; x1 += k2 + 1u;
  TF_R(17) TF_R(29) TF_R(16) TF_R(24)  x0 += k2; x1 += k0 + 2u;
  TF_R(13) TF_R(15) TF_R(26) TF_R(6)   x0 += k0; x1 += k1 + 3u;
  TF_R(17) TF_R(29) TF_R(16) TF_R(24)  x0 += k1; x1 += k2 + 4u;
  TF_R(13) TF_R(15) TF_R(26) TF_R(6)   x0 += k2; x1 += k0 + 5u;
#undef TF_R
}

__device__ __forceinline__ float erfinv_xla(float x) {
  float w = -log1pf(-(x * x));
  float p;
  if (w < 5.0f) {
    w = w - 2.5f;
    p = 2.81022636e-08f;
    p = fmaf(p, w, 3.43273939e-07f);
    p = fmaf(p, w, -3.5233877e-06f);
    p = fmaf(p, w, -4.39150654e-06f);
    p = fmaf(p, w, 0.00021858087f);
    p = fmaf(p, w, -0.00125372503f);
    p = fmaf(p, w, -0.00417768164f);
    p = fmaf(p, w, 0.246640727f);
    p = fmaf(p, w, 1.50140941f);
  } else {
    w = sqrtf(w) - 3.0f;
    p = -0.000200214257f;
    p = fmaf(p, w, 0.000100950558f);
    p = fmaf(p, w, 0.00134934322f);
    p = fmaf(p, w, -0.00367342844f);
    p = fmaf(p, w, 0.00573950773f);
    p = fmaf(p, w, -0.0076224613f);
    p = fmaf(p, w, 0.00943887047f);
    p = fmaf(p, w, 1.00167406f);
    p = fmaf(p, w, 2.83297682f);
  }
  return p * x;
}

__device__ __forceinline__ float jax_normal(uint32_t k0, uint32_t k1, uint32_t e) {
  uint32_t x0 = 0u, x1 = e;
  tf_block(k0, k1, x0, x1);
  uint32_t bits = x0 ^ x1;
  float u = __uint_as_float((bits >> 9) | 0x3f800000u) - 1.0f;
  float v = __fadd_rn(__fmul_rn(u, 2.0f), -0x1.fffffep-1f);
  v = fmaxf(v, -0x1.fffffep-1f);
  return __fmul_rn((float)1.4142135623730951, erfinv_xla(v));
}

// accurate sin of an EXACT f32 argument: f64 Cody-Waite reduction (verified R9)
__device__ __forceinline__ float sin_acc(float xf) {
  double x = (double)xf;
  double kd = rint(x * 6.3661977236758138e-01);
  double r = fma(-kd, 1.5707963267948966e+00, x);
  r = fma(-kd, 6.1232339957367660e-17, r);
  float rf = (float)r;
  float y = rf * rf;
  float ps = fmaf(y, 2.7557319e-06f, -1.9841270e-04f);
  ps = fmaf(y, ps, 8.3333335e-03f);
  ps = fmaf(y, ps, -0.16666667f);
  float s = fmaf(rf * y, ps, rf);
  float pc = fmaf(y, -2.7557319e-07f, 2.4801587e-05f);
  pc = fmaf(y, pc, -1.3888889e-03f);
  pc = fmaf(y, pc, 4.1666668e-02f);
  pc = fmaf(y, pc, -0.5f);
  float c = fmaf(y, pc, 1.0f);
  int q = ((int)kd) & 3;
  float rs = (q & 1) ? c : s;
  return (q & 2) ? -rs : rs;
}

__device__ __forceinline__ float apply_act(float v, int act) {
  switch (act) {
    case ACT_LRELU:    return v >= 0.0f ? v : 0.1f * v;
    case ACT_SOFTPLUS: return fmaxf(v, 0.0f) + log1pf(expf(-fabsf(v)));
    case ACT_SIGMOID:  return 1.0f / (1.0f + expf(-v));
  }
  return v;
}

// ---------------- async-staged conv paths, 4t/thread, counted vmcnt ----------
// Block = 256 thr = 4 waves. Wave og = tid>>6 owns 4 outputs; lane owns 4
// adjacent t (tl = 4*lane). Block tile: 16 outputs x 256 t. Chunk = 16 cc,
// double-buffered DMA staging. Per chunk: issue(c+1) -> s_waitcnt vmcnt(N)
// [waits only chunk-c loads] -> s_barrier -> compute(c) -> s_barrier.
// x staging extent is XN=4352 slots (17 uniform DMAs/thread); slots with
// cc>=CH or j>=258 or OOB t source a zeroed buffer and live in harmless pad.
// Weight region starts at buf+XN -> NO overlap with x staging (R18 bugfix).
// Staged values identical to the verified R13 layout -> FMA chains cc
// ascending, k 0..2, bias-seeded -> bitwise identical to reference.

// K=3 conv: 20 DMAs per thread per chunk (17 x + 3 w).
__device__ __forceinline__ void conv3_async(
    const float* __restrict__ x, const float* __restrict__ w,
    const float* __restrict__ bias, float* __restrict__ y,
    const float* __restrict__ zbuf,
    int Cin, int Cout, int o0, int act, int b, int t0, float* smem) {
  int tid = threadIdx.x;
  int lane = tid & 63, og = tid >> 6;
  int tl = 4 * lane;
  int t = t0 + tl;
  int obase = o0 + og * 4;
  float acc[4][4];
#pragma unroll
  for (int i = 0; i < 4; ++i) {
    float bv = (obase + i < Cout) ? bias[obase + i] : 0.0f;
#pragma unroll
    for (int j = 0; j < 4; ++j) acc[i][j] = bv;
  }
  const int nch = Cin / CH;
  auto issue = [&](int c, float* buf) {
    int cb = c * CH;
#pragma unroll
    for (int k = 0; k < 17; ++k) {
      int idx = tid + 256 * k;  // < 4352 = XN
      int cc = idx / ROWS, j = idx - cc * ROWS;
      int tt = t0 - 1 + j;
      const float* src = (cc < CH && j < 258 && tt >= 0 && tt < T_)
          ? x + ((size_t)b * Cin + cb + cc) * T_ + tt : zbuf;
      __builtin_amdgcn_global_load_lds((gp1_t)src, (lp3_t)(buf + idx), 4, 0, 0);
    }
#pragma unroll
    for (int k = 0; k < 3; ++k) {
      int p = tid + 256 * k;  // < 768 = 16cc x 16o x 3
      int cc = p / 48, r = p - cc * 48;
      int oo = r / 3, kk = r - oo * 3;
      const float* src = (o0 + oo < Cout)
          ? w + ((size_t)(o0 + oo) * Cin + cb + cc) * 3 + kk : zbuf;
      __builtin_amdgcn_global_load_lds((gp1_t)src, (lp3_t)(buf + XN + p), 4, 0, 0);
    }
  };
  issue(0, smem);
  for (int c = 0; c < nch; ++c) {
    const float* cur = smem + (c & 1) * BUFA;
    if (c + 1 < nch) {
      issue(c + 1, smem + ((c + 1) & 1) * BUFA);
      asm volatile("s_waitcnt vmcnt(20)" ::: "memory");
    } else {
      asm volatile("s_waitcnt vmcnt(0)" ::: "memory");
    }
    __builtin_amdgcn_s_barrier();
    __builtin_amdgcn_sched_barrier(0);
    const float* sxf = cur;             // [16][260]
    const float* swf = cur + XN;        // [16][48]
    for (int cc = 0; cc < CH; ++cc) {
      const float* row = sxf + cc * ROWS + tl;   // 16B aligned
      float4 X0 = *(const float4*)row;           // x[t-1..t+2]
      float2 X1 = *(const float2*)(row + 4);     // x[t+3..t+4]
      float xw[6] = {X0.x, X0.y, X0.z, X0.w, X1.x, X1.y};
      const float4* wq = (const float4*)(swf + cc * 48 + og * 12);
      float4 W0 = wq[0], W1 = wq[1], W2 = wq[2];
      float wl[12] = {W0.x, W0.y, W0.z, W0.w, W1.x, W1.y, W1.z, W1.w,
                      W2.x, W2.y, W2.z, W2.w};
#pragma unroll
      for (int i = 0; i < 4; ++i) {
        float w0 = wl[3 * i], w1 = wl[3 * i + 1], w2 = wl[3 * i + 2];
#pragma unroll
        for (int j = 0; j < 4; ++j) {
          acc[i][j] = fmaf(xw[j],     w0, acc[i][j]);
          acc[i][j] = fmaf(xw[j + 1], w1, acc[i][j]);
          acc[i][j] = fmaf(xw[j + 2], w2, acc[i][j]);
        }
      }
    }
    __builtin_amdgcn_sched_barrier(0);
    __builtin_amdgcn_s_barrier();  // all reads of cur done before re-staging
  }
#pragma unroll
  for (int i = 0; i < 4; ++i) {
    int o = obase + i;
    if (o < Cout) {
      float* yp = y + ((size_t)b * Cout + o) * T_ + t;
      if (t + 4 <= T_) {
        *(float4*)yp = make_float4(apply_act(acc[i][0], act), apply_act(acc[i][1], act),
                                   apply_act(acc[i][2], act), apply_act(acc[i][3], act));
      } else {
#pragma unroll
        for (int j = 0; j < 4; ++j)
          if (t + j < T_) yp[j] = apply_act(acc[i][j], act);
      }
    }
  }
}

// Fused depthwise-K3 -> pointwise: 19 DMAs per thread per chunk (17 x + 2 w).
// dw recomputed in-register (chain identical to reference dw); pw cc
// ascending, bias-seeded -> bitwise identical.
__device__ __forceinline__ void dwpw_async(
    const float* __restrict__ x, const float* __restrict__ wd,
    const float* __restrict__ bd, const float* __restrict__ wp,
    const float* __restrict__ bp, float* __restrict__ y,
    const float* __restrict__ zbuf,
    int Cin, int Cout, int o0, int act, int b, int t0, float* smem) {
  int tid = threadIdx.x;
  int lane = tid & 63, og = tid >> 6;
  int tl = 4 * lane;
  int t = t0 + tl;
  int obase = o0 + og * 4;
  float acc[4][4];
#pragma unroll
  for (int i = 0; i < 4; ++i) {
    float bv = (obase + i < Cout) ? bp[obase + i] : 0.0f;
#pragma unroll
    for (int j = 0; j < 4; ++j) acc[i][j] = bv;
  }
  const int nch = Cin / CH;
  auto issue = [&](int c, float* buf) {
    int cb = c * CH;
#pragma unroll
    for (int k = 0; k < 17; ++k) {
      int idx = tid + 256 * k;  // < 4352 = XN
      int cc = idx / ROWS, j = idx - cc * ROWS;
      int tt = t0 - 1 + j;
      const float* src = (cc < CH && j < 258 && tt >= 0 && tt < T_)
          ? x + ((size_t)b * Cin + cb + cc) * T_ + tt : zbuf;
      __builtin_amdgcn_global_load_lds((gp1_t)src, (lp3_t)(buf + idx), 4, 0, 0);
    }
#pragma unroll
    for (int k = 0; k < 2; ++k) {
      int p = tid + 256 * k;  // < 512: [swd 16x4 = 64][swp 16x16 = 256][pad]
      const float* src = zbuf;
      if (p < 64) {
        int cc = p >> 2, q = p & 3;
        src = (q < 3) ? wd + (size_t)(cb + cc) * 3 + q : bd + cb + cc;
      } else if (p < 320) {
        int pp = p - 64;
        int cc = pp >> 4, oo = pp & 15;
        if (o0 + oo < Cout) src = wp + (size_t)(o0 + oo) * Cin + cb + cc;
      }
      __builtin_amdgcn_global_load_lds((gp1_t)src, (lp3_t)(buf + XN + p), 4, 0, 0);
    }
  };
  issue(0, smem);
  for (int c = 0; c < nch; ++c) {
    const float* cur = smem + (c & 1) * BUFA;
    if (c + 1 < nch) {
      issue(c + 1, smem + ((c + 1) & 1) * BUFA);
      asm volatile("s_waitcnt vmcnt(19)" ::: "memory");
    } else {
      asm volatile("s_waitcnt vmcnt(0)" ::: "memory");
    }
    __builtin_amdgcn_s_barrier();
    __builtin_amdgcn_sched_barrier(0);
    const float* sxf  = cur;             // [16][260]
    const float* swdf = cur + XN;        // [16][4]
    const float* swpf = cur + XN + 64;   // [16][16]
    for (int cc = 0; cc < CH; ++cc) {
      const float* row = sxf + cc * ROWS + tl;
      float4 X0 = *(const float4*)row;
      float2 X1 = *(const float2*)(row + 4);
      float xw[6] = {X0.x, X0.y, X0.z, X0.w, X1.x, X1.y};
      float4 D = *(const float4*)(swdf + cc * 4);
      float d[4];
#pragma unroll
      for (int j = 0; j < 4; ++j)
        d[j] = fmaf(xw[j], D.x, fmaf(xw[j + 1], D.y, fmaf(xw[j + 2], D.z, D.w)));
      float4 Wp = *(const float4*)(swpf + cc * 16 + og * 4);
      float wl[4] = {Wp.x, Wp.y, Wp.z, Wp.w};
#pragma unroll
      for (int i = 0; i < 4; ++i)
#pragma unroll
        for (int j = 0; j < 4; ++j)
          acc[i][j] = fmaf(d[j], wl[i], acc[i][j]);
    }
    __builtin_amdgcn_sched_barrier(0);
    __builtin_amdgcn_s_barrier();
  }
#pragma unroll
  for (int i = 0; i < 4; ++i) {
    int o = obase + i;
    if (o < Cout) {
      float* yp = y + ((size_t)b * Cout + o) * T_ + t;
      if (t + 4 <= T_) {
        *(float4*)yp = make_float4(apply_act(acc[i][0], act), apply_act(acc[i][1], act),
                                   apply_act(acc[i][2], act), apply_act(acc[i][3], act));
      } else {
#pragma unroll
        for (int j = 0; j < 4; ++j)
          if (t + j < T_) yp[j] = apply_act(acc[i][j], act);
      }
    }
  }
}

// K=1 pointwise, weights-once (verified).
__device__ __forceinline__ void pw_stream(
    const float* __restrict__ x, const float* __restrict__ w,
    const float* __restrict__ bias, float* __restrict__ y,
    int Cin, int Cout, int o0, int act, int b, int t0, float* smem) {
  for (int idx = threadIdx.x; idx < 16 * Cin; idx += 256) {
    int oo = idx / Cin, cc = idx - oo * Cin;
    smem[cc * 16 + oo] = (o0 + oo < Cout) ? w[(size_t)(o0 + oo) * Cin + cc] : 0.0f;
  }
  __syncthreads();
  int lane = threadIdx.x & 63, og = threadIdx.x >> 6;
  int t = t0 + lane;
  int obase = o0 + og * 4;
  float acc[4];
#pragma unroll
  for (int i = 0; i < 4; ++i)
    acc[i] = (obase + i < Cout) ? bias[obase + i] : 0.0f;
  if (t < T_) {
    const float* xr = x + (size_t)b * Cin * T_ + t;
#pragma unroll 4
    for (int cc = 0; cc < Cin; ++cc) {
      float xv = xr[(size_t)cc * T_];
      float4 Wp = *(const float4*)(smem + cc * 16 + og * 4);
      acc[0] = fmaf(xv, Wp.x, acc[0]);
      acc[1] = fmaf(xv, Wp.y, acc[1]);
      acc[2] = fmaf(xv, Wp.z, acc[2]);
      acc[3] = fmaf(xv, Wp.w, acc[3]);
    }
#pragma unroll
    for (int i = 0; i < 4; ++i) {
      int o = obase + i;
      if (o < Cout) y[((size_t)b * Cout + o) * T_ + t] = apply_act(acc[i], act);
    }
  }
}

// ---- terms + RWR level-1 body (grid-stride; verified) ----
__device__ void terms_body(const float* __restrict__ f0, float* __restrict__ A1,
                           int base, int stride) {
  const float RINV = (float)(500.0 / 120000.0);
  for (int gid = base; gid < B_ * N1_; gid += stride) {
    int b = gid / N1_, w = gid - b * N1_;
    const float* f0b = f0 + (size_t)b * T_;
    float* a = A1 + (size_t)b * L_ + (size_t)w * 16;
    float S = 0.0f;
    int lbase = w * 16;
    for (int i = 0; i < 16; ++i) {
      int l = lbase + i;
      float pos = __fsub_rn(__fmul_rn(__fadd_rn((float)l, 0.5f), RINV), 0.5f);
      pos = fminf(fmaxf(pos, 0.0f), 499.0f);
      int lo = (int)floorf(pos);
      int hi = lo + 1; hi = hi < (T_ - 1) ? hi : (T_ - 1);
      float wt = __fsub_rn(pos, (float)lo);
      float omw = __fsub_rn(1.0f, wt);
      float f0up = __fadd_rn(__fmul_rn(f0b[lo], omw), __fmul_rn(f0b[hi], wt));
      float trm = __fdiv_rn(__fmul_rn((float)6.283185307179586, f0up), 24000.0f);
      S = __fadd_rn(S, trm);
      a[i] = S;
    }
  }
}

// ---- fused RWR mid-chain body: l2,l3,l4,l5,e3,e2 in one 256-thr block ----
__device__ void rwr_body(const float* __restrict__ A1, float* __restrict__ A2,
                         float* __restrict__ A3, float* __restrict__ A4,
                         float* __restrict__ E5, float* __restrict__ E3o,
                         float* __restrict__ E2o) {
  int tid = threadIdx.x;
  for (int gid = tid; gid < B_ * N2_; gid += 256) {
    int b = gid / N2_, w = gid - b * N2_;
    float S = 0.0f;
    for (int m = 0; m < 16; ++m) {
      int i = w * 16 + m;
      float v = (i < N1_) ? A1[(size_t)b * L_ + (size_t)i * 16 + 15] : 0.0f;
      S = __fadd_rn(S, v);
      A2[(size_t)b * N2P_ + i] = S;
    }
  }
  __syncthreads();
  for (int gid = tid; gid < B_ * N3_; gid += 256) {
    int b = gid / N3_, w = gid - b * N3_;
    float S = 0.0f;
    for (int m = 0; m < 16; ++m) {
      int i = w * 16 + m;
      float v = (i < N2_) ? A2[(size_t)b * N2P_ + (size_t)i * 16 + 15] : 0.0f;
      S = __fadd_rn(S, v);
      A3[(size_t)b * N3P_ + i] = S;
    }
  }
  __syncthreads();
  for (int gid = tid; gid < B_ * N4_; gid += 256) {
    int b = gid / N4_, w = gid - b * N4_;
    float S = 0.0f;
    for (int m = 0; m < 16; ++m) {
      int i = w * 16 + m;
      float v = (i < N3_) ? A3[(size_t)b * N3P_ + (size_t)i * 16 + 15] : 0.0f;
      S = __fadd_rn(S, v);
      A4[(size_t)b * N4P_ + i] = S;
    }
  }
  __syncthreads();
  if (tid < B_) {
    E5[tid * N4_ + 0] = 0.0f;
    E5[tid * N4_ + 1] = A4[(size_t)tid * N4P_ + 15];
  }
  __syncthreads();
  for (int gid = tid; gid < B_ * N3_; gid += 256) {
    int b = gid / N3_, k = gid - b * N3_;
    float v = 0.0f;
    if (k > 0) {
      int i = k - 1;
      v = __fadd_rn(E5[b * N4_ + (i >> 4)], A4[(size_t)b * N4P_ + i]);
    }
    E3o[b * N3_ + k] = v;
  }
  __syncthreads();
  for (int gid = tid; gid < B_ * N2_; gid += 256) {
    int b = gid / N2_, j = gid - b * N2_;
    float v = 0.0f;
    if (j > 0) {
      int i = j - 1;
      v = __fadd_rn(E3o[b * N3_ + (i >> 4)], A3[(size_t)b * N3P_ + i]);
    }
    E2o[b * N2_ + j] = v;
  }
}

// ---------------- merged layer kernels (16o x 256t tiles, grid.x = 2) --------
// L1: fm1 conv3 (y 0..15) | vq1 conv3 (y 16..23) | ha1 dwpw (y 24..39)
//     | terms+rwr-l1 (y 40, 8 blocks grid-stride)
__global__ void __launch_bounds__(256) conv_l1(
    const float* __restrict__ cond, const float* __restrict__ f0,
    const float* __restrict__ fw1, const float* __restrict__ fb1,
    const float* __restrict__ vw1, const float* __restrict__ vb1,
    const float* __restrict__ hw1, const float* __restrict__ hb1,
    const float* __restrict__ hw2, const float* __restrict__ hb2,
    float* __restrict__ fmA, float* __restrict__ vqB, float* __restrict__ haB,
    float* __restrict__ A1, const float* __restrict__ zbuf) {
  __shared__ __align__(16) float smem[2 * BUFA];
  int yy = blockIdx.y, b = blockIdx.z, t0 = blockIdx.x * 256;
  if (yy < 16) {
    conv3_async(cond, fw1, fb1, fmA, zbuf, 128, 256, yy * 16, ACT_LRELU, b, t0, smem);
  } else if (yy < 24) {
    conv3_async(cond, vw1, vb1, vqB, zbuf, 128, 128, (yy - 16) * 16, ACT_LRELU, b, t0, smem);
  } else if (yy < 40) {
    dwpw_async(cond, hw1, hb1, hw2, hb2, haB, zbuf, 128, 256, (yy - 24) * 16, ACT_LRELU, b, t0, smem);
  } else {
    int base = (blockIdx.z * 2 + blockIdx.x) * 256 + threadIdx.x;
    terms_body(f0, A1, base, 2048);
  }
}

// L2: fm2 conv3 (y 0..15) | vq2 conv3 (y 16..19) | ha2 dwpw (y 20..35)
//     | rwr mid-chain (y 36, one block)
__global__ void __launch_bounds__(256) conv_l2(
    const float* __restrict__ fmA, const float* __restrict__ vqB,
    const float* __restrict__ haB,
    const float* __restrict__ fw2, const float* __restrict__ fb2,
    const float* __restrict__ vw2, const float* __restrict__ vb2,
    const float* __restrict__ hw3, const float* __restrict__ hb3,
    const float* __restrict__ hw4, const float* __restrict__ hb4,
    float* __restrict__ fmC, float* __restrict__ vqC, float* __restrict__ haC,
    const float* __restrict__ A1, float* __restrict__ A2, float* __restrict__ A3,
    float* __restrict__ A4, float* __restrict__ E5, float* __restrict__ E3o,
    float* __restrict__ E2o, const float* __restrict__ zbuf) {
  __shared__ __align__(16) float smem[2 * BUFA];
  int yy = blockIdx.y, b = blockIdx.z, t0 = blockIdx.x * 256;
  if (yy < 16) {
    conv3_async(fmA, fw2, fb2, fmC, zbuf, 256, 256, yy * 16, ACT_LRELU, b, t0, smem);
  } else if (yy < 20) {
    conv3_async(vqB, vw2, vb2, vqC, zbuf, 128, 64, (yy - 16) * 16, ACT_LRELU, b, t0, smem);
  } else if (yy < 36) {
    dwpw_async(haB, hw3, hb3, hw4, hb4, haC, zbuf, 256, 256, (yy - 20) * 16, ACT_LRELU, b, t0, smem);
  } else {
    if (blockIdx.x != 0 || blockIdx.z != 0) return;
    rwr_body(A1, A2, A3, A4, E5, E3o, E2o);
  }
}

// L3: ha5 pw 256->100 softplus (y 0..6) | fm3 pw 256->10 (y 7) | vq3 pw 64->3 (y 8)
__global__ void __launch_bounds__(256) conv_l3(
    const float* __restrict__ haC, const float* __restrict__ fmC,
    const float* __restrict__ vqC,
    const float* __restrict__ hw5, const float* __restrict__ hb5,
    const float* __restrict__ fw3, const float* __restrict__ fb3,
    const float* __restrict__ vw3, const float* __restrict__ vb3,
    float* __restrict__ ha, float* __restrict__ fp, float* __restrict__ qv) {
  __shared__ __align__(16) float smem[4096];  // 16o x 256cc
  int yy = blockIdx.y, b = blockIdx.z, t0 = blockIdx.x * 64;
  if (yy < 7) {
    pw_stream(haC, hw5, hb5, ha, 256, 100, yy * 16, ACT_SOFTPLUS, b, t0, smem);
  } else if (yy == 7) {
    pw_stream(fmC, fw3, fb3, fp, 256, 10, 0, ACT_NONE, b, t0, smem);
  } else {
    pw_stream(vqC, vw3, vb3, qv, 64, 3, 0, ACT_SIGMOID, b, t0, smem);
  }
}

// ---------------- main synthesis kernel (shaped + rwr_e1 fused; verified R15)
__global__ void __launch_bounds__(256) main_kernel(
    const float* __restrict__ A1, const float* __restrict__ A2,
    const float* __restrict__ E2o,
    const float* __restrict__ ha, const float* __restrict__ fp,
    const float* __restrict__ q,
    const float* __restrict__ f0, float* __restrict__ out,
    uint32_t k10, uint32_t k11, uint32_t k20, uint32_t k21, uint32_t k30, uint32_t k31) {
  const float RINV = (float)(500.0 / 120000.0);
  int b = blockIdx.y;
  int l0 = blockIdx.x * 256;
  int l = l0 + threadIdx.x;
  __shared__ float ls[4][NH_];
  __shared__ float sff[4][5], snm[4][5];
  float p0 = __fsub_rn(__fmul_rn(__fadd_rn((float)l0, 0.5f), RINV), 0.5f);
  p0 = fminf(fmaxf(p0, 0.0f), 499.0f);
  int lo0 = (int)floorf(p0);
  if (threadIdx.x < 40) {
    int j = threadIdx.x / 10, h = threadIdx.x - j * 10;
    int col = lo0 + j; col = col < (T_ - 1) ? col : (T_ - 1);
    float v = fp[((size_t)b * 10 + h) * T_ + col];
    if (h < 5) {
      sff[j][h] = 200.0f + 3300.0f * (1.0f / (1.0f + expf(-v)));
    } else {
      float bw = 50.0f + 150.0f * (fmaxf(v, 0.0f) + log1pf(expf(-fabsf(v))));
      snm[j][h - 5] = bw * bw;
    }
  }
  __syncthreads();
  for (int i = threadIdx.x; i < 4 * NH_; i += 256) {
    int j = i / NH_, h = i - j * NH_;
    int col = lo0 + j; col = col < (T_ - 1) ? col : (T_ - 1);
    float hfreq = (float)(h + 1) * f0[(size_t)b * T_ + col];
    float g = 1.0f;
    for (int ii = 0; ii < 5; ++ii) {
      float d = hfreq - sff[j][ii];
      float den = d * d + snm[j][ii];
      float res = snm[j][ii] / fmaxf(den, 1e-5f);
      g = g * (0.8f + 0.2f * res);
    }
    ls[j][h] = ha[((size_t)b * NH_ + h) * T_ + col] * g;
  }
  __syncthreads();
  if (l >= L_) return;

  float pos = __fsub_rn(__fmul_rn(__fadd_rn((float)l, 0.5f), RINV), 0.5f);
  pos = fminf(fmaxf(pos, 0.0f), 499.0f);
  int lo = (int)floorf(pos);
  int hi = lo + 1; hi = hi < (T_ - 1) ? hi : (T_ - 1);
  float w = __fsub_rn(pos, (float)lo);
  float omw = __fsub_rn(1.0f, w);

  const float* f0b = f0 + (size_t)b * T_;
  float f0up = __fadd_rn(__fmul_rn(f0b[lo], omw), __fmul_rn(f0b[hi], w));
  const float* qb = q + (size_t)b * 3 * T_;
  float q0 = __fadd_rn(__fmul_rn(qb[lo], omw), __fmul_rn(qb[hi], w));
  float q1 = __fadd_rn(__fmul_rn(qb[T_ + lo], omw), __fmul_rn(qb[T_ + hi], w));
  float q2 = __fadd_rn(__fmul_rn(qb[2 * T_ + lo], omw), __fmul_rn(qb[2 * T_ + hi], w));
  float jit = __fmul_rn(q0, 0.05f);
  float shm = __fmul_rn(q1, 0.15f);
  float brt = __fmul_rn(q2, 0.3f);

  uint32_t e = (uint32_t)(b * L_ + l);
  float n1 = jax_normal(k10, k11, e);
  float n2 = jax_normal(k20, k21, e);
  float n3 = jax_normal(k30, k31, e);

  float e1v = 0.0f;
  int r = l >> 4;
  if (r > 0) {
    int i = r - 1;
    e1v = __fadd_rn(E2o[b * N2_ + (i >> 4)], A2[(size_t)b * N2P_ + i]);
  }
  float phf = __fadd_rn(e1v, A1[(size_t)b * L_ + l]);
  float jph = __fadd_rn(phf, __fmul_rn(jit, n1));

  int jlo = lo - lo0;
  int jhi = hi - lo0; jhi = jhi < 3 ? jhi : 3;

  float acc = 0.0f;
  for (int h = 1; h <= NH_; ++h) {
    float amp = __fadd_rn(__fmul_rn(ls[jlo][h - 1], omw), __fmul_rn(ls[jhi][h - 1], w));
    float hf = (float)h;
    float arg = __fmul_rn(jph, hf);
    float s = sin_acc(arg);
    float m = (__fmul_rn(hf, f0up) < 12000.0f) ? 1.0f : 0.0f;
    acc = __fadd_rn(acc, __fmul_rn(__fmul_rn(amp, s), m));
  }
  float env = __fadd_rn(1.0f, __fmul_rn(n2, shm));
  out[(size_t)b * L_ + l] = __fadd_rn(__fmul_rn(acc, env), __fmul_rn(n3, brt));
}

extern "C" void kernel_launch(void* const* d_in, const int* in_sizes, int n_in,
                              void* d_out, int out_size, void* d_ws, size_t ws_size,
                              hipStream_t stream) {
  const float* f0    = (const float*)d_in[0];
  const float* cond  = (const float*)d_in[1];
  const float* ha_w1 = (const float*)d_in[2];
  const float* ha_b1 = (const float*)d_in[3];
  const float* ha_w2 = (const float*)d_in[4];
  const float* ha_b2 = (const float*)d_in[5];
  const float* ha_w3 = (const float*)d_in[6];
  const float* ha_b3 = (const float*)d_in[7];
  const float* ha_w4 = (const float*)d_in[8];
  const float* ha_b4 = (const float*)d_in[9];
  const float* ha_w5 = (const float*)d_in[10];
  const float* ha_b5 = (const float*)d_in[11];
  const float* fm_w1 = (const float*)d_in[12];
  const float* fm_b1 = (const float*)d_in[13];
  const float* fm_w2 = (const float*)d_in[14];
  const float* fm_b2 = (const float*)d_in[15];
  const float* fm_w3 = (const float*)d_in[16];
  const float* fm_b3 = (const float*)d_in[17];
  const float* vq_w1 = (const float*)d_in[18];
  const float* vq_b1 = (const float*)d_in[19];
  const float* vq_w2 = (const float*)d_in[20];
  const float* vq_b2 = (const float*)d_in[21];
  const float* vq_w3 = (const float*)d_in[22];
  const float* vq_b3 = (const float*)d_in[23];
  float* out = (float*)d_out;

  // split(key(42), 3), foldlike/partitionable (verified)
  uint32_t kw[3][2];
  for (uint32_t j = 0; j < 3; ++j) {
    uint32_t x0 = 0u, x1 = j;
    tf_block(0u, 42u, x0, x1);
    kw[j][0] = x0; kw[j][1] = x1;
  }

  // workspace layout (floats)
  float* ws = (float*)d_ws;
  size_t off = 0;
  auto take = [&](size_t n) { float* p = ws + off; off += (n + 3) & ~(size_t)3; return p; };
  float* fmA = take(512000);
  float* haB = take(512000);
  float* fmC = take(512000);
  float* haC = take(512000);
  float* vqB = take(256000);
  float* vqC = take(128000);
  float* A1  = take((size_t)B_ * L_);
  float* A2  = take((size_t)B_ * N2P_);
  float* A3  = take((size_t)B_ * N3P_);
  float* A4  = take((size_t)B_ * N4P_);
  float* E5  = take((size_t)B_ * N4_);
  float* E3o = take((size_t)B_ * N3_);
  float* E2o = take((size_t)B_ * N2_);
  float* zbuf = take(64);
  // aliases into dead conv buffers (liveness verified):
  float* ha = fmA;            // written L3; fmA dead after L2
  float* fp = vqB;            // written L3; vqB dead after L2
  float* qv = vqB + 20480;    // written L3

  // zero source for OOB/pad async loads (graph-capturable)
  hipMemsetAsync(zbuf, 0, 64 * sizeof(float), stream);

  // merged conv layers (terms in L1, rwr mid-chain in L2) — async staging,
  // 16o x 256t tiles
  conv_l1<<<dim3(2, 41, B_), 256, 0, stream>>>(
      cond, f0, fm_w1, fm_b1, vq_w1, vq_b1, ha_w1, ha_b1, ha_w2, ha_b2,
      fmA, vqB, haB, A1, zbuf);
  conv_l2<<<dim3(2, 37, B_), 256, 0, stream>>>(
      fmA, vqB, haB, fm_w2, fm_b2, vq_w2, vq_b2, ha_w3, ha_b3, ha_w4, ha_b4,
      fmC, vqC, haC, A1, A2, A3, A4, E5, E3o, E2o, zbuf);
  conv_l3<<<dim3(8, 9, B_), 256, 0, stream>>>(
      haC, fmC, vqC, ha_w5, ha_b5, fm_w3, fm_b3, vq_w3, vq_b3, ha, fp, qv);
  // synthesis (shaped + rwr_e1 fused)
  main_kernel<<<dim3((L_ + 255) / 256, B_), 256, 0, stream>>>(
      A1, A2, E2o, ha, fp, qv, f0, out,
      kw[0][0], kw[0][1], kw[1][0], kw[1][1], kw[2][0], kw[2][1]);
  (void)in_sizes; (void)n_in; (void)out_size; (void)ws_size;
}

// Round 20
// 274.876 us; speedup vs baseline: 1.1499x; 1.1499x over previous
//
#include <hip/hip_runtime.h>
#include <stdint.h>

#define B_ 4
#define T_ 500
#define L_ 120000
#define NH_ 100
// RWR(16) level sizes (verified R9 — DO NOT TOUCH)
#define N1_ 7500
#define N2_ 469
#define N2P_ 7504
#define N3_ 30
#define N3P_ 480
#define N4_ 2
#define N4P_ 32

#define ACT_NONE 0
#define ACT_LRELU 1
#define ACT_SOFTPLUS 2
#define ACT_SIGMOID 3

#define CH3 32    // cc chunk
#define SXW3 132  // sx row stride (130 used: t0-1 .. t0+128)

// ---------------- Threefry2x32-20 (verified R9) ----------------
__host__ __device__ __forceinline__ uint32_t tf_rotl(uint32_t v, int d) {
  return (v << d) | (v >> (32 - d));
}
__host__ __device__ __forceinline__ void tf_block(uint32_t k0, uint32_t k1,
                                                  uint32_t& x0, uint32_t& x1) {
  uint32_t k2 = k0 ^ k1 ^ 0x1BD11BDAu;
  x0 += k0; x1 += k1;
#define TF_R(d) x0 += x1; x1 = tf_rotl(x1, (d)); x1 ^= x0;
  TF_R(13) TF_R(15) TF_R(26) TF_R(6)   x0 += k1; x1 += k2 + 1u;
  TF_R(17) TF_R(29) TF_R(16) TF_R(24)  x0 += k2; x1 += k0 + 2u;
  TF_R(13) TF_R(15) TF_R(26) TF_R(6)   x0 += k0; x1 += k1 + 3u;
  TF_R(17) TF_R(29) TF_R(16) TF_R(24)  x0 += k1; x1 += k2 + 4u;
  TF_R(13) TF_R(15) TF_R(26) TF_R(6)   x0 += k2; x1 += k0 + 5u;
#undef TF_R
}

__device__ __forceinline__ float erfinv_xla(float x) {
  float w = -log1pf(-(x * x));
  float p;
  if (w < 5.0f) {
    w = w - 2.5f;
    p = 2.81022636e-08f;
    p = fmaf(p, w, 3.43273939e-07f);
    p = fmaf(p, w, -3.5233877e-06f);
    p = fmaf(p, w, -4.39150654e-06f);
    p = fmaf(p, w, 0.00021858087f);
    p = fmaf(p, w, -0.00125372503f);
    p = fmaf(p, w, -0.00417768164f);
    p = fmaf(p, w, 0.246640727f);
    p = fmaf(p, w, 1.50140941f);
  } else {
    w = sqrtf(w) - 3.0f;
    p = -0.000200214257f;
    p = fmaf(p, w, 0.000100950558f);
    p = fmaf(p, w, 0.00134934322f);
    p = fmaf(p, w, -0.00367342844f);
    p = fmaf(p, w, 0.00573950773f);
    p = fmaf(p, w, -0.0076224613f);
    p = fmaf(p, w, 0.00943887047f);
    p = fmaf(p, w, 1.00167406f);
    p = fmaf(p, w, 2.83297682f);
  }
  return p * x;
}

__device__ __forceinline__ float jax_normal(uint32_t k0, uint32_t k1, uint32_t e) {
  uint32_t x0 = 0u, x1 = e;
  tf_block(k0, k1, x0, x1);
  uint32_t bits = x0 ^ x1;
  float u = __uint_as_float((bits >> 9) | 0x3f800000u) - 1.0f;
  float v = __fadd_rn(__fmul_rn(u, 2.0f), -0x1.fffffep-1f);
  v = fmaxf(v, -0x1.fffffep-1f);
  return __fmul_rn((float)1.4142135623730951, erfinv_xla(v));
}

// accurate sin of an EXACT f32 argument: f64 Cody-Waite reduction (verified R9)
__device__ __forceinline__ float sin_acc(float xf) {
  double x = (double)xf;
  double kd = rint(x * 6.3661977236758138e-01);
  double r = fma(-kd, 1.5707963267948966e+00, x);
  r = fma(-kd, 6.1232339957367660e-17, r);
  float rf = (float)r;
  float y = rf * rf;
  float ps = fmaf(y, 2.7557319e-06f, -1.9841270e-04f);
  ps = fmaf(y, ps, 8.3333335e-03f);
  ps = fmaf(y, ps, -0.16666667f);
  float s = fmaf(rf * y, ps, rf);
  float pc = fmaf(y, -2.7557319e-07f, 2.4801587e-05f);
  pc = fmaf(y, pc, -1.3888889e-03f);
  pc = fmaf(y, pc, 4.1666668e-02f);
  pc = fmaf(y, pc, -0.5f);
  float c = fmaf(y, pc, 1.0f);
  int q = ((int)kd) & 3;
  float rs = (q & 1) ? c : s;
  return (q & 2) ? -rs : rs;
}

__device__ __forceinline__ float apply_act(float v, int act) {
  switch (act) {
    case ACT_LRELU:    return v >= 0.0f ? v : 0.1f * v;
    case ACT_SOFTPLUS: return fmaxf(v, 0.0f) + log1pf(expf(-fabsf(v)));
    case ACT_SIGMOID:  return 1.0f / (1.0f + expf(-v));
  }
  return v;
}

// ---------------- LDS-chunked conv paths (R10-verified, best measured) -------
// Block = 256 thr = 4 waves. Wave og = tid>>6 owns 4 outputs (weight LDS reads
// are whole-wave same-address broadcasts -> conflict-free). Lane owns 2
// adjacent t (tl = 2*lane). Block tile: 16 outputs x 128 t. Chunk = 32 cc with
// register-prefetch of next chunk issued after the second barrier.
// FMA chain per output: cc ascending across chunks, k 0..2, acc seeded from
// bias -> bitwise identical to reference.

// K=3 conv. LDS: sx[32][132] (130 used) + sw[32][52] = 23552 B.
__device__ __forceinline__ void conv3_tile(
    const float* __restrict__ x, const float* __restrict__ w,
    const float* __restrict__ bias, float* __restrict__ y,
    int Cin, int Cout, int o0, int act, int b, int t0, float* smem) {
  float* sxf = smem;                // [32][SXW3], row j: x[t0-1+j], j<130
  float* swf = smem + CH3 * SXW3;   // [32][52]: [cc][o_local*3+k]
  int tid = threadIdx.x;
  int lane = tid & 63, og = tid >> 6;
  int tl = 2 * lane;
  int t = t0 + tl;
  int obase = o0 + og * 4;
  float acc[4][2];
#pragma unroll
  for (int i = 0; i < 4; ++i) {
    float bv = (obase + i < Cout) ? bias[obase + i] : 0.0f;
    acc[i][0] = bv; acc[i][1] = bv;
  }
  float rx[17], rw[6];
  const int nch = Cin / CH3;
  auto ld = [&](int c) {
    int cb = c * CH3;
#pragma unroll
    for (int k = 0; k < 17; ++k) {
      int idx = tid + 256 * k;
      float v = 0.0f;
      if (idx < CH3 * 130) {
        int cc = idx / 130, j = idx - cc * 130;
        int tt = t0 - 1 + j;
        if (tt >= 0 && tt < T_) v = x[((size_t)b * Cin + cb + cc) * T_ + tt];
      }
      rx[k] = v;
    }
#pragma unroll
    for (int k = 0; k < 6; ++k) {
      int idx = tid + 256 * k;  // < 1536 = 16o x 96
      int oo = idx / 96, r = idx - oo * 96;
      rw[k] = (o0 + oo < Cout) ? w[((size_t)(o0 + oo) * Cin + cb) * 3 + r] : 0.0f;
    }
  };
  ld(0);
  for (int c = 0; c < nch; ++c) {
    __syncthreads();
#pragma unroll
    for (int k = 0; k < 17; ++k) {
      int idx = tid + 256 * k;
      if (idx < CH3 * 130) {
        int cc = idx / 130, j = idx - cc * 130;
        sxf[cc * SXW3 + j] = rx[k];
      }
    }
#pragma unroll
    for (int k = 0; k < 6; ++k) {
      int idx = tid + 256 * k;
      int oo = idx / 96, r = idx - oo * 96;
      swf[(r / 3) * 52 + oo * 3 + (r % 3)] = rw[k];
    }
    __syncthreads();
    if (c + 1 < nch) ld(c + 1);
    for (int cc = 0; cc < CH3; ++cc) {
      const float* row = sxf + cc * SXW3 + tl;
      float2 xa = *(const float2*)row;        // x[t-1], x[t]
      float2 xb = *(const float2*)(row + 2);  // x[t+1], x[t+2]
      const float4* wq = (const float4*)(swf + cc * 52 + og * 12);
      float4 W0 = wq[0], W1 = wq[1], W2 = wq[2];
      float wl[12] = {W0.x, W0.y, W0.z, W0.w, W1.x, W1.y, W1.z, W1.w,
                      W2.x, W2.y, W2.z, W2.w};
#pragma unroll
      for (int i = 0; i < 4; ++i) {
        float w0 = wl[3 * i], w1 = wl[3 * i + 1], w2 = wl[3 * i + 2];
        acc[i][0] = fmaf(xa.x, w0, acc[i][0]);
        acc[i][0] = fmaf(xa.y, w1, acc[i][0]);
        acc[i][0] = fmaf(xb.x, w2, acc[i][0]);
        acc[i][1] = fmaf(xa.y, w0, acc[i][1]);
        acc[i][1] = fmaf(xb.x, w1, acc[i][1]);
        acc[i][1] = fmaf(xb.y, w2, acc[i][1]);
      }
    }
  }
#pragma unroll
  for (int i = 0; i < 4; ++i) {
    int o = obase + i;
    if (o < Cout) {
      if (t < T_)     y[((size_t)b * Cout + o) * T_ + t]     = apply_act(acc[i][0], act);
      if (t + 1 < T_) y[((size_t)b * Cout + o) * T_ + t + 1] = apply_act(acc[i][1], act);
    }
  }
}

// Fused depthwise-K3 -> pointwise. dw recomputed in-register (chain identical
// to reference dw); pw cc ascending, bias-seeded -> bitwise identical.
// LDS: sx[32][132] + swd[32][4] + swp[32][16] = 17536 B.
__device__ __forceinline__ void dwpw_tile(
    const float* __restrict__ x, const float* __restrict__ wd,
    const float* __restrict__ bd, const float* __restrict__ wp,
    const float* __restrict__ bp, float* __restrict__ y,
    int Cin, int Cout, int o0, int act, int b, int t0, float* smem) {
  float* sxf  = smem;                // [32][SXW3]
  float* swdf = smem + CH3 * SXW3;   // [32][4] {w0,w1,w2,bias}
  float* swpf = swdf + CH3 * 4;      // [32][16] [cc][o_local]
  int tid = threadIdx.x;
  int lane = tid & 63, og = tid >> 6;
  int tl = 2 * lane;
  int t = t0 + tl;
  int obase = o0 + og * 4;
  float acc[4][2];
#pragma unroll
  for (int i = 0; i < 4; ++i) {
    float bv = (obase + i < Cout) ? bp[obase + i] : 0.0f;
    acc[i][0] = bv; acc[i][1] = bv;
  }
  float rx[17], rwp[2], rwd1 = 0.0f;
  const int nch = Cin / CH3;
  auto ld = [&](int c) {
    int cb = c * CH3;
#pragma unroll
    for (int k = 0; k < 17; ++k) {
      int idx = tid + 256 * k;
      float v = 0.0f;
      if (idx < CH3 * 130) {
        int cc = idx / 130, j = idx - cc * 130;
        int tt = t0 - 1 + j;
        if (tt >= 0 && tt < T_) v = x[((size_t)b * Cin + cb + cc) * T_ + tt];
      }
      rx[k] = v;
    }
    if (tid < CH3 * 4) {
      int cc = tid >> 2, q = tid & 3;
      rwd1 = (q < 3) ? wd[(size_t)(cb + cc) * 3 + q] : bd[cb + cc];
    }
#pragma unroll
    for (int k = 0; k < 2; ++k) {
      int idx = tid + 256 * k;  // < 512 = 16o x 32cc
      int oo = idx >> 5, cc = idx & 31;
      rwp[k] = (o0 + oo < Cout) ? wp[(size_t)(o0 + oo) * Cin + cb + cc] : 0.0f;
    }
  };
  ld(0);
  for (int c = 0; c < nch; ++c) {
    __syncthreads();
#pragma unroll
    for (int k = 0; k < 17; ++k) {
      int idx = tid + 256 * k;
      if (idx < CH3 * 130) {
        int cc = idx / 130, j = idx - cc * 130;
        sxf[cc * SXW3 + j] = rx[k];
      }
    }
    if (tid < CH3 * 4) swdf[tid] = rwd1;
#pragma unroll
    for (int k = 0; k < 2; ++k) {
      int idx = tid + 256 * k;
      int oo = idx >> 5, cc = idx & 31;
      swpf[cc * 16 + oo] = rwp[k];
    }
    __syncthreads();
    if (c + 1 < nch) ld(c + 1);
    for (int cc = 0; cc < CH3; ++cc) {
      const float* row = sxf + cc * SXW3 + tl;
      float2 xa = *(const float2*)row;
      float2 xb = *(const float2*)(row + 2);
      float4 D = *(const float4*)(swdf + cc * 4);
      float d0 = fmaf(xa.x, D.x, fmaf(xa.y, D.y, fmaf(xb.x, D.z, D.w)));
      float d1 = fmaf(xa.y, D.x, fmaf(xb.x, D.y, fmaf(xb.y, D.z, D.w)));
      float4 Wp = *(const float4*)(swpf + cc * 16 + og * 4);
      acc[0][0] = fmaf(d0, Wp.x, acc[0][0]);
      acc[1][0] = fmaf(d0, Wp.y, acc[1][0]);
      acc[2][0] = fmaf(d0, Wp.z, acc[2][0]);
      acc[3][0] = fmaf(d0, Wp.w, acc[3][0]);
      acc[0][1] = fmaf(d1, Wp.x, acc[0][1]);
      acc[1][1] = fmaf(d1, Wp.y, acc[1][1]);
      acc[2][1] = fmaf(d1, Wp.z, acc[2][1]);
      acc[3][1] = fmaf(d1, Wp.w, acc[3][1]);
    }
  }
#pragma unroll
  for (int i = 0; i < 4; ++i) {
    int o = obase + i;
    if (o < Cout) {
      if (t < T_)     y[((size_t)b * Cout + o) * T_ + t]     = apply_act(acc[i][0], act);
      if (t + 1 < T_) y[((size_t)b * Cout + o) * T_ + t + 1] = apply_act(acc[i][1], act);
    }
  }
}

// K=1 pointwise, weights-once (verified).
__device__ __forceinline__ void pw_stream(
    const float* __restrict__ x, const float* __restrict__ w,
    const float* __restrict__ bias, float* __restrict__ y,
    int Cin, int Cout, int o0, int act, int b, int t0, float* smem) {
  for (int idx = threadIdx.x; idx < 16 * Cin; idx += 256) {
    int oo = idx / Cin, cc = idx - oo * Cin;
    smem[cc * 16 + oo] = (o0 + oo < Cout) ? w[(size_t)(o0 + oo) * Cin + cc] : 0.0f;
  }
  __syncthreads();
  int lane = threadIdx.x & 63, og = threadIdx.x >> 6;
  int t = t0 + lane;
  int obase = o0 + og * 4;
  float acc[4];
#pragma unroll
  for (int i = 0; i < 4; ++i)
    acc[i] = (obase + i < Cout) ? bias[obase + i] : 0.0f;
  if (t < T_) {
    const float* xr = x + (size_t)b * Cin * T_ + t;
#pragma unroll 4
    for (int cc = 0; cc < Cin; ++cc) {
      float xv = xr[(size_t)cc * T_];
      float4 Wp = *(const float4*)(smem + cc * 16 + og * 4);
      acc[0] = fmaf(xv, Wp.x, acc[0]);
      acc[1] = fmaf(xv, Wp.y, acc[1]);
      acc[2] = fmaf(xv, Wp.z, acc[2]);
      acc[3] = fmaf(xv, Wp.w, acc[3]);
    }
#pragma unroll
    for (int i = 0; i < 4; ++i) {
      int o = obase + i;
      if (o < Cout) y[((size_t)b * Cout + o) * T_ + t] = apply_act(acc[i], act);
    }
  }
}

// ---- terms + RWR level-1 body (grid-stride; verified) ----
__device__ void terms_body(const float* __restrict__ f0, float* __restrict__ A1,
                           int base, int stride) {
  const float RINV = (float)(500.0 / 120000.0);
  for (int gid = base; gid < B_ * N1_; gid += stride) {
    int b = gid / N1_, w = gid - b * N1_;
    const float* f0b = f0 + (size_t)b * T_;
    float* a = A1 + (size_t)b * L_ + (size_t)w * 16;
    float S = 0.0f;
    int lbase = w * 16;
    for (int i = 0; i < 16; ++i) {
      int l = lbase + i;
      float pos = __fsub_rn(__fmul_rn(__fadd_rn((float)l, 0.5f), RINV), 0.5f);
      pos = fminf(fmaxf(pos, 0.0f), 499.0f);
      int lo = (int)floorf(pos);
      int hi = lo + 1; hi = hi < (T_ - 1) ? hi : (T_ - 1);
      float wt = __fsub_rn(pos, (float)lo);
      float omw = __fsub_rn(1.0f, wt);
      float f0up = __fadd_rn(__fmul_rn(f0b[lo], omw), __fmul_rn(f0b[hi], wt));
      float trm = __fdiv_rn(__fmul_rn((float)6.283185307179586, f0up), 24000.0f);
      S = __fadd_rn(S, trm);
      a[i] = S;
    }
  }
}

// ---- fused RWR mid-chain body: l2,l3,l4,l5,e3,e2 in one 256-thr block ----
__device__ void rwr_body(const float* __restrict__ A1, float* __restrict__ A2,
                         float* __restrict__ A3, float* __restrict__ A4,
                         float* __restrict__ E5, float* __restrict__ E3o,
                         float* __restrict__ E2o) {
  int tid = threadIdx.x;
  for (int gid = tid; gid < B_ * N2_; gid += 256) {
    int b = gid / N2_, w = gid - b * N2_;
    float S = 0.0f;
    for (int m = 0; m < 16; ++m) {
      int i = w * 16 + m;
      float v = (i < N1_) ? A1[(size_t)b * L_ + (size_t)i * 16 + 15] : 0.0f;
      S = __fadd_rn(S, v);
      A2[(size_t)b * N2P_ + i] = S;
    }
  }
  __syncthreads();
  for (int gid = tid; gid < B_ * N3_; gid += 256) {
    int b = gid / N3_, w = gid - b * N3_;
    float S = 0.0f;
    for (int m = 0; m < 16; ++m) {
      int i = w * 16 + m;
      float v = (i < N2_) ? A2[(size_t)b * N2P_ + (size_t)i * 16 + 15] : 0.0f;
      S = __fadd_rn(S, v);
      A3[(size_t)b * N3P_ + i] = S;
    }
  }
  __syncthreads();
  for (int gid = tid; gid < B_ * N4_; gid += 256) {
    int b = gid / N4_, w = gid - b * N4_;
    float S = 0.0f;
    for (int m = 0; m < 16; ++m) {
      int i = w * 16 + m;
      float v = (i < N3_) ? A3[(size_t)b * N3P_ + (size_t)i * 16 + 15] : 0.0f;
      S = __fadd_rn(S, v);
      A4[(size_t)b * N4P_ + i] = S;
    }
  }
  __syncthreads();
  if (tid < B_) {
    E5[tid * N4_ + 0] = 0.0f;
    E5[tid * N4_ + 1] = A4[(size_t)tid * N4P_ + 15];
  }
  __syncthreads();
  for (int gid = tid; gid < B_ * N3_; gid += 256) {
    int b = gid / N3_, k = gid - b * N3_;
    float v = 0.0f;
    if (k > 0) {
      int i = k - 1;
      v = __fadd_rn(E5[b * N4_ + (i >> 4)], A4[(size_t)b * N4P_ + i]);
    }
    E3o[b * N3_ + k] = v;
  }
  __syncthreads();
  for (int gid = tid; gid < B_ * N2_; gid += 256) {
    int b = gid / N2_, j = gid - b * N2_;
    float v = 0.0f;
    if (j > 0) {
      int i = j - 1;
      v = __fadd_rn(E3o[b * N3_ + (i >> 4)], A3[(size_t)b * N3P_ + i]);
    }
    E2o[b * N2_ + j] = v;
  }
}

// ---------------- merged layer kernels (R10 grids) ----------------
// L1: fm1 conv3 (y 0..15) | vq1 conv3 (y 16..23) | ha1 dwpw (y 24..39)
//     | terms+rwr-l1 (y 40, 16 blocks grid-stride)
__global__ void __launch_bounds__(256) conv_l1(
    const float* __restrict__ cond, const float* __restrict__ f0,
    const float* __restrict__ fw1, const float* __restrict__ fb1,
    const float* __restrict__ vw1, const float* __restrict__ vb1,
    const float* __restrict__ hw1, const float* __restrict__ hb1,
    const float* __restrict__ hw2, const float* __restrict__ hb2,
    float* __restrict__ fmA, float* __restrict__ vqB, float* __restrict__ haB,
    float* __restrict__ A1) {
  __shared__ __align__(16) float smem[CH3 * SXW3 + CH3 * 52];
  int yy = blockIdx.y, b = blockIdx.z, t0 = blockIdx.x * 128;
  if (yy < 16) {
    conv3_tile(cond, fw1, fb1, fmA, 128, 256, yy * 16, ACT_LRELU, b, t0, smem);
  } else if (yy < 24) {
    conv3_tile(cond, vw1, vb1, vqB, 128, 128, (yy - 16) * 16, ACT_LRELU, b, t0, smem);
  } else if (yy < 40) {
    dwpw_tile(cond, hw1, hb1, hw2, hb2, haB, 128, 256, (yy - 24) * 16, ACT_LRELU, b, t0, smem);
  } else {
    int base = (blockIdx.z * 4 + blockIdx.x) * 256 + threadIdx.x;
    terms_body(f0, A1, base, 4096);
  }
}

// L2: fm2 conv3 (y 0..15) | vq2 conv3 (y 16..19) | ha2 dwpw (y 20..35)
//     | rwr mid-chain (y 36, one block)
__global__ void __launch_bounds__(256) conv_l2(
    const float* __restrict__ fmA, const float* __restrict__ vqB,
    const float* __restrict__ haB,
    const float* __restrict__ fw2, const float* __restrict__ fb2,
    const float* __restrict__ vw2, const float* __restrict__ vb2,
    const float* __restrict__ hw3, const float* __restrict__ hb3,
    const float* __restrict__ hw4, const float* __restrict__ hb4,
    float* __restrict__ fmC, float* __restrict__ vqC, float* __restrict__ haC,
    const float* __restrict__ A1, float* __restrict__ A2, float* __restrict__ A3,
    float* __restrict__ A4, float* __restrict__ E5, float* __restrict__ E3o,
    float* __restrict__ E2o) {
  __shared__ __align__(16) float smem[CH3 * SXW3 + CH3 * 52];
  int yy = blockIdx.y, b = blockIdx.z, t0 = blockIdx.x * 128;
  if (yy < 16) {
    conv3_tile(fmA, fw2, fb2, fmC, 256, 256, yy * 16, ACT_LRELU, b, t0, smem);
  } else if (yy < 20) {
    conv3_tile(vqB, vw2, vb2, vqC, 128, 64, (yy - 16) * 16, ACT_LRELU, b, t0, smem);
  } else if (yy < 36) {
    dwpw_tile(haB, hw3, hb3, hw4, hb4, haC, 256, 256, (yy - 20) * 16, ACT_LRELU, b, t0, smem);
  } else {
    if (blockIdx.x != 0 || blockIdx.z != 0) return;
    rwr_body(A1, A2, A3, A4, E5, E3o, E2o);
  }
}

// L3: ha5 pw 256->100 softplus (y 0..6) | fm3 pw 256->10 (y 7) | vq3 pw 64->3 (y 8)
__global__ void __launch_bounds__(256) conv_l3(
    const float* __restrict__ haC, const float* __restrict__ fmC,
    const float* __restrict__ vqC,
    const float* __restrict__ hw5, const float* __restrict__ hb5,
    const float* __restrict__ fw3, const float* __restrict__ fb3,
    const float* __restrict__ vw3, const float* __restrict__ vb3,
    float* __restrict__ ha, float* __restrict__ fp, float* __restrict__ qv) {
  __shared__ __align__(16) float smem[4096];  // 16o x 256cc
  int yy = blockIdx.y, b = blockIdx.z, t0 = blockIdx.x * 64;
  if (yy < 7) {
    pw_stream(haC, hw5, hb5, ha, 256, 100, yy * 16, ACT_SOFTPLUS, b, t0, smem);
  } else if (yy == 7) {
    pw_stream(fmC, fw3, fb3, fp, 256, 10, 0, ACT_NONE, b, t0, smem);
  } else {
    pw_stream(vqC, vw3, vb3, qv, 64, 3, 0, ACT_SIGMOID, b, t0, smem);
  }
}

// ---------------- main synthesis kernel ---------------------------------
// shaped_kernel fused in: ff/nm computed from fp (same f32 expressions, same
// order as the old shaped_kernel), gain applied to ha at the 4 staged columns
// -> ls values bitwise identical to the old sh buffer. rwr_e1 inlined.
__global__ void __launch_bounds__(256) main_kernel(
    const float* __restrict__ A1, const float* __restrict__ A2,
    const float* __restrict__ E2o,
    const float* __restrict__ ha, const float* __restrict__ fp,
    const float* __restrict__ q,
    const float* __restrict__ f0, float* __restrict__ out,
    uint32_t k10, uint32_t k11, uint32_t k20, uint32_t k21, uint32_t k30, uint32_t k31) {
  const float RINV = (float)(500.0 / 120000.0);
  int b = blockIdx.y;
  int l0 = blockIdx.x * 256;
  int l = l0 + threadIdx.x;
  __shared__ float ls[4][NH_];
  __shared__ float sff[4][5], snm[4][5];
  float p0 = __fsub_rn(__fmul_rn(__fadd_rn((float)l0, 0.5f), RINV), 0.5f);
  p0 = fminf(fmaxf(p0, 0.0f), 499.0f);
  int lo0 = (int)floorf(p0);
  if (threadIdx.x < 40) {
    int j = threadIdx.x / 10, h = threadIdx.x - j * 10;
    int col = lo0 + j; col = col < (T_ - 1) ? col : (T_ - 1);
    float v = fp[((size_t)b * 10 + h) * T_ + col];
    if (h < 5) {
      sff[j][h] = 200.0f + 3300.0f * (1.0f / (1.0f + expf(-v)));
    } else {
      float bw = 50.0f + 150.0f * (fmaxf(v, 0.0f) + log1pf(expf(-fabsf(v))));
      snm[j][h - 5] = bw * bw;
    }
  }
  __syncthreads();
  for (int i = threadIdx.x; i < 4 * NH_; i += 256) {
    int j = i / NH_, h = i - j * NH_;
    int col = lo0 + j; col = col < (T_ - 1) ? col : (T_ - 1);
    float hfreq = (float)(h + 1) * f0[(size_t)b * T_ + col];
    float g = 1.0f;
    for (int ii = 0; ii < 5; ++ii) {
      float d = hfreq - sff[j][ii];
      float den = d * d + snm[j][ii];
      float res = snm[j][ii] / fmaxf(den, 1e-5f);
      g = g * (0.8f + 0.2f * res);
    }
    ls[j][h] = ha[((size_t)b * NH_ + h) * T_ + col] * g;
  }
  __syncthreads();
  if (l >= L_) return;

  float pos = __fsub_rn(__fmul_rn(__fadd_rn((float)l, 0.5f), RINV), 0.5f);
  pos = fminf(fmaxf(pos, 0.0f), 499.0f);
  int lo = (int)floorf(pos);
  int hi = lo + 1; hi = hi < (T_ - 1) ? hi : (T_ - 1);
  float w = __fsub_rn(pos, (float)lo);
  float omw = __fsub_rn(1.0f, w);

  const float* f0b = f0 + (size_t)b * T_;
  float f0up = __fadd_rn(__fmul_rn(f0b[lo], omw), __fmul_rn(f0b[hi], w));
  const float* qb = q + (size_t)b * 3 * T_;
  float q0 = __fadd_rn(__fmul_rn(qb[lo], omw), __fmul_rn(qb[hi], w));
  float q1 = __fadd_rn(__fmul_rn(qb[T_ + lo], omw), __fmul_rn(qb[T_ + hi], w));
  float q2 = __fadd_rn(__fmul_rn(qb[2 * T_ + lo], omw), __fmul_rn(qb[2 * T_ + hi], w));
  float jit = __fmul_rn(q0, 0.05f);
  float shm = __fmul_rn(q1, 0.15f);
  float brt = __fmul_rn(q2, 0.3f);

  uint32_t e = (uint32_t)(b * L_ + l);
  float n1 = jax_normal(k10, k11, e);
  float n2 = jax_normal(k20, k21, e);
  float n3 = jax_normal(k30, k31, e);

  float e1v = 0.0f;
  int r = l >> 4;
  if (r > 0) {
    int i = r - 1;
    e1v = __fadd_rn(E2o[b * N2_ + (i >> 4)], A2[(size_t)b * N2P_ + i]);
  }
  float phf = __fadd_rn(e1v, A1[(size_t)b * L_ + l]);
  float jph = __fadd_rn(phf, __fmul_rn(jit, n1));

  int jlo = lo - lo0;
  int jhi = hi - lo0; jhi = jhi < 3 ? jhi : 3;

  float acc = 0.0f;
  for (int h = 1; h <= NH_; ++h) {
    float amp = __fadd_rn(__fmul_rn(ls[jlo][h - 1], omw), __fmul_rn(ls[jhi][h - 1], w));
    float hf = (float)h;
    float arg = __fmul_rn(jph, hf);
    float s = sin_acc(arg);
    float m = (__fmul_rn(hf, f0up) < 12000.0f) ? 1.0f : 0.0f;
    acc = __fadd_rn(acc, __fmul_rn(__fmul_rn(amp, s), m));
  }
  float env = __fadd_rn(1.0f, __fmul_rn(n2, shm));
  out[(size_t)b * L_ + l] = __fadd_rn(__fmul_rn(acc, env), __fmul_rn(n3, brt));
}

extern "C" void kernel_launch(void* const* d_in, const int* in_sizes, int n_in,
                              void* d_out, int out_size, void* d_ws, size_t ws_size,
                              hipStream_t stream) {
  const float* f0    = (const float*)d_in[0];
  const float* cond  = (const float*)d_in[1];
  const float* ha_w1 = (const float*)d_in[2];
  const float* ha_b1 = (const float*)d_in[3];
  const float* ha_w2 = (const float*)d_in[4];
  const float* ha_b2 = (const float*)d_in[5];
  const float* ha_w3 = (const float*)d_in[6];
  const float* ha_b3 = (const float*)d_in[7];
  const float* ha_w4 = (const float*)d_in[8];
  const float* ha_b4 = (const float*)d_in[9];
  const float* ha_w5 = (const float*)d_in[10];
  const float* ha_b5 = (const float*)d_in[11];
  const float* fm_w1 = (const float*)d_in[12];
  const float* fm_b1 = (const float*)d_in[13];
  const float* fm_w2 = (const float*)d_in[14];
  const float* fm_b2 = (const float*)d_in[15];
  const float* fm_w3 = (const float*)d_in[16];
  const float* fm_b3 = (const float*)d_in[17];
  const float* vq_w1 = (const float*)d_in[18];
  const float* vq_b1 = (const float*)d_in[19];
  const float* vq_w2 = (const float*)d_in[20];
  const float* vq_b2 = (const float*)d_in[21];
  const float* vq_w3 = (const float*)d_in[22];
  const float* vq_b3 = (const float*)d_in[23];
  float* out = (float*)d_out;

  // split(key(42), 3), foldlike/partitionable (verified)
  uint32_t kw[3][2];
  for (uint32_t j = 0; j < 3; ++j) {
    uint32_t x0 = 0u, x1 = j;
    tf_block(0u, 42u, x0, x1);
    kw[j][0] = x0; kw[j][1] = x1;
  }

  // workspace layout (floats)
  float* ws = (float*)d_ws;
  size_t off = 0;
  auto take = [&](size_t n) { float* p = ws + off; off += (n + 3) & ~(size_t)3; return p; };
  float* fmA = take(512000);
  float* haB = take(512000);
  float* fmC = take(512000);
  float* haC = take(512000);
  float* vqB = take(256000);
  float* vqC = take(128000);
  float* A1  = take((size_t)B_ * L_);
  float* A2  = take((size_t)B_ * N2P_);
  float* A3  = take((size_t)B_ * N3P_);
  float* A4  = take((size_t)B_ * N4P_);
  float* E5  = take((size_t)B_ * N4_);
  float* E3o = take((size_t)B_ * N3_);
  float* E2o = take((size_t)B_ * N2_);
  // aliases into dead conv buffers (liveness verified):
  float* ha = fmA;            // written L3; fmA dead after L2
  float* fp = vqB;            // written L3; vqB dead after L2
  float* qv = vqB + 20480;    // written L3

  // merged conv layers (terms in L1, rwr mid-chain in L2) — R10 grids
  conv_l1<<<dim3(4, 41, B_), 256, 0, stream>>>(
      cond, f0, fm_w1, fm_b1, vq_w1, vq_b1, ha_w1, ha_b1, ha_w2, ha_b2,
      fmA, vqB, haB, A1);
  conv_l2<<<dim3(4, 37, B_), 256, 0, stream>>>(
      fmA, vqB, haB, fm_w2, fm_b2, vq_w2, vq_b2, ha_w3, ha_b3, ha_w4, ha_b4,
      fmC, vqC, haC, A1, A2, A3, A4, E5, E3o, E2o);
  conv_l3<<<dim3(8, 9, B_), 256, 0, stream>>>(
      haC, fmC, vqC, ha_w5, ha_b5, fm_w3, fm_b3, vq_w3, vq_b3, ha, fp, qv);
  // synthesis (shaped + rwr_e1 fused)
  main_kernel<<<dim3((L_ + 255) / 256, B_), 256, 0, stream>>>(
      A1, A2, E2o, ha, fp, qv, f0, out,
      kw[0][0], kw[0][1], kw[1][0], kw[1][1], kw[2][0], kw[2][1]);
  (void)in_sizes; (void)n_in; (void)out_size; (void)ws_size;
}